// Round 11
// baseline (465.501 us; speedup 1.0000x reference)
//
#include <hip/hip_runtime.h>

// Problem constants (match reference)
#define BB 4096
#define DD 16
#define MM 4
#define RR 2048
#define CC 10
#define TB 4
#define RPT (RR / 256)
#define REPS 5   // ABLATION round: every variant dispatch >43us -> own counter row

// variant bits
#define V_TAB    1   // rebuild tables (incl. 3 barriers + exp) each rep
#define V_GATHER 2   // real LDS gathers (else synthetic p)
#define V_FMA    4   // wsum loads + acc FMAs
#define V_STORE  8   // FS pack/store + phase-4 norm_fs stores
#define V_FULL   (V_TAB | V_GATHER | V_FMA | V_STORE)

typedef __attribute__((ext_vector_type(4))) float f32x4;
typedef __attribute__((ext_vector_type(2))) float f32x2;
typedef __attribute__((ext_vector_type(4))) unsigned short u16x4;

__device__ __forceinline__ unsigned short f2bf(float x) {
    union { float f; unsigned u; } v; v.f = x;
    unsigned b = v.u + 0x7FFFu + ((v.u >> 16) & 1u);
    return (unsigned short)(b >> 16);
}
__device__ __forceinline__ float bf2f(unsigned short h) {
    union { unsigned u; float f; } v; v.u = ((unsigned)h) << 16;
    return v.f;
}

// ---------------- prep kernel (unchanged) ----------------
__global__ __launch_bounds__(256) void prep_kernel(
    const float* __restrict__ cons, const int* __restrict__ rules,
    float* __restrict__ wsum4a, float* __restrict__ wsum4b,
    float* __restrict__ wsum2, unsigned int* __restrict__ codes)
{
    int gid = blockIdx.x * 256 + threadIdx.x;
    if (gid < RR * CC) {
        int r = gid / CC, c = gid - r * CC;
        const float* cr = cons + (size_t)r * (DD + 1) * CC + c;
        float s = 0.0f;
#pragma unroll
        for (int j = 0; j < DD + 1; ++j) s += cr[j * CC];
        if (c < 4)      wsum4a[r * 4 + c] = s;
        else if (c < 8) wsum4b[r * 4 + (c - 4)] = s;
        else            wsum2[r * 2 + (c - 8)] = s;
    }
    if (gid < RR) {
        const int* rrp = rules + gid * DD;
        unsigned int code = 0;
#pragma unroll
        for (int g = 0; g < 4; ++g) {
            unsigned int byt = 0;
#pragma unroll
            for (int k = 0; k < 4; ++k)
                byt |= (((unsigned int)rrp[g * 4 + k]) & 3u) << (2 * k);
            code |= byt << (8 * g);
        }
        codes[gid] = code;
    }
}

// ---------------- main kernel: R10 structure + runtime variant mask ----------
// ONE binary for all variants (identical VGPR/LDS/occupancy) so marginal
// dispatch-time differences attribute cleanly to the skipped phase.
__global__ __launch_bounds__(256, 4) void anfis_main(
    const float* __restrict__ x, const float* __restrict__ centers,
    const float* __restrict__ widths, const f32x4* __restrict__ wsum4a,
    const f32x4* __restrict__ wsum4b, const f32x2* __restrict__ wsum2,
    const unsigned int* __restrict__ codes,
    float* __restrict__ out, float* __restrict__ norm_fs, float* __restrict__ x_ext,
    int variant)
{
    __shared__ __align__(16) char pool[4 * 256 * sizeof(f32x4)];
    f32x4 (*QUAD4)[256] = (f32x4 (*)[256])pool;  // [g][e] -> 4 rows
    float (*RED)[68]    = (float (*)[68])pool;   // [40][64+pad]

    __shared__ u16x4 FS[RR];
    __shared__ float MF[TB][64];
    __shared__ f32x4 PAIR4[8][16];
    __shared__ float xs[TB][DD];
    __shared__ float sx[TB];
    __shared__ float wpart[4][TB];
    __shared__ float invl[TB];
    __shared__ float oscale[TB];
    __shared__ float part2[TB * CC][4];

    const int tid = threadIdx.x;
    const int b0 = blockIdx.x * TB;
    const int lane = tid & 63;
    const int wv = tid >> 6;

    // ---- phase 1a (once) ----
    if (tid < TB * (DD + 1)) {
        int row = tid / (DD + 1), col = tid % (DD + 1);
        float v = (col < DD) ? x[(b0 + row) * DD + col] : 1.0f;
        if (col < DD) xs[row][col] = v;
        x_ext[(b0 + row) * (DD + 1) + col] = v;
    }
    __syncthreads();
    if (tid < TB) {
        float s = 1.0f;
#pragma unroll
        for (int d = 0; d < DD; ++d) s += xs[tid][d];
        sx[tid] = s;
    }

#define BUILD_TABLES() do { \
        { int row = tid >> 6, dm = tid & 63, d = dm >> 2, m = dm & 3; \
          float c = centers[d * MM + m]; \
          float w = widths[d * MM + m]; \
          float z = xs[row][d] - c; \
          MF[row][dm] = expf(-(z * z) / (2.0f * w * w)); } \
        __syncthreads(); \
        if (tid < 8 * 16) { \
            int p = tid >> 4, e = tid & 15; \
            int i0 = e & 3, i1 = e >> 2; \
            f32x4 v; \
            _Pragma("unroll") \
            for (int row = 0; row < TB; ++row) \
                v[row] = MF[row][(2 * p) * 4 + i0] * MF[row][(2 * p + 1) * 4 + i1]; \
            PAIR4[p][e] = v; \
        } \
        __syncthreads(); \
        _Pragma("unroll") \
        for (int i = tid; i < 4 * 256; i += 256) { \
            int g = i >> 8, e = i & 255; \
            QUAD4[g][e] = PAIR4[2 * g][e & 15] * PAIR4[2 * g + 1][e >> 4]; \
        } \
        __syncthreads(); \
    } while (0)

    BUILD_TABLES();  // pre-loop build (all variants; keeps NOTAB correct-ish)

#pragma unroll 1
    for (int rep = 0; rep < REPS; ++rep) {
        __syncthreads();  // prior-rep RED/part2 reads done before pool rewrite

        if (variant & V_TAB) BUILD_TABLES();

        // ---- phase 2 ----
        float acc[TB][CC];
#pragma unroll
        for (int row = 0; row < TB; ++row)
#pragma unroll
            for (int c = 0; c < CC; ++c) acc[row][c] = 0.0f;

        f32x4 svec = {0.0f, 0.0f, 0.0f, 0.0f};

#pragma unroll 1
        for (int j = 0; j < RPT; ++j) {
            int r = tid + 256 * j;
            unsigned int code = codes[r];
            f32x4 p;
            if (variant & V_GATHER) {
                f32x4 q0 = QUAD4[0][code & 255u];
                f32x4 q1 = QUAD4[1][(code >> 8) & 255u];
                f32x4 q2 = QUAD4[2][(code >> 16) & 255u];
                f32x4 q3 = QUAD4[3][code >> 24];
                p = (q0 * q1) * (q2 * q3);
            } else {
                // synthetic, strictly positive, ~same magnitude scale
                p[0] = (float)((code       ) & 255u) * 1e-3f + 1e-3f;
                p[1] = (float)((code >>  8 ) & 255u) * 1e-3f + 1e-3f;
                p[2] = (float)((code >> 16 ) & 255u) * 1e-3f + 1e-3f;
                p[3] = (float)((code >> 24 )       ) * 1e-3f + 1e-3f;
            }
            svec += p;

            if (variant & V_STORE) {
                u16x4 fh;
                fh.x = f2bf(p[0]); fh.y = f2bf(p[1]);
                fh.z = f2bf(p[2]); fh.w = f2bf(p[3]);
                FS[r] = fh;
            }

            if (variant & V_FMA) {
                const f32x4 wa = wsum4a[r];
                const f32x4 wb = wsum4b[r];
                const f32x2 wcp = wsum2[r];
                const float wc[CC] = {wa.x, wa.y, wa.z, wa.w, wb.x,
                                      wb.y, wb.z, wb.w, wcp.x, wcp.y};
#pragma unroll
                for (int row = 0; row < TB; ++row)
#pragma unroll
                    for (int c = 0; c < CC; ++c)
                        acc[row][c] = fmaf(p[row], wc[c], acc[row][c]);
            }
        }

        // ---- phase 3 (always) ----
#pragma unroll
        for (int row = 0; row < TB; ++row) {
            float s = svec[row];
#pragma unroll
            for (int off = 32; off > 0; off >>= 1) s += __shfl_xor(s, off, 64);
            if (lane == 0) wpart[wv][row] = s;
        }
        __syncthreads();
        if (tid < TB) {
            float t = wpart[0][tid] + wpart[1][tid] + wpart[2][tid] + wpart[3][tid];
            float inv = 1.0f / (t + 1e-9f);
            invl[tid] = inv;
            oscale[tid] = sx[tid] * inv;
        }
        __syncthreads();

        const float inv0 = invl[0], inv1 = invl[1], inv2 = invl[2], inv3 = invl[3];

        // ---- phase 4 ----
        if (variant & V_STORE) {
#pragma unroll 1
            for (int j = 0; j < RPT; ++j) {
                int r = tid + 256 * j;
                u16x4 fh = FS[r];
                norm_fs[(size_t)(b0 + 0) * RR + r] = bf2f(fh.x) * inv0;
                norm_fs[(size_t)(b0 + 1) * RR + r] = bf2f(fh.y) * inv1;
                norm_fs[(size_t)(b0 + 2) * RR + r] = bf2f(fh.z) * inv2;
                norm_fs[(size_t)(b0 + 3) * RR + r] = bf2f(fh.w) * inv3;
            }
        } else {
            asm volatile("" :: "v"(inv0), "v"(inv1), "v"(inv2), "v"(inv3));
        }

        // ---- phase 5 (always) ----
#pragma unroll
        for (int row = 0; row < TB; ++row) {
#pragma unroll
            for (int c = 0; c < CC; ++c) {
                float s = acc[row][c];
                s += __shfl_xor(s, 1, 64);
                s += __shfl_xor(s, 2, 64);
                if ((lane & 3) == 0) RED[row * CC + c][wv * 16 + (lane >> 2)] = s;
            }
        }
        __syncthreads();
        if (tid < 160) {
            int v = tid % 40, ch = tid / 40;
            float s = 0.0f;
            int base = ch * 16;
#pragma unroll
            for (int i = 0; i < 16; ++i) s += RED[v][base + i];
            part2[v][ch] = s;
        }
        __syncthreads();
        if (tid < TB * CC) {
            float val = part2[tid][0] + part2[tid][1] + part2[tid][2] + part2[tid][3];
            int row = tid / CC, c = tid % CC;
            out[(b0 + row) * CC + c] = oscale[row] * val;
        }
    }
#undef BUILD_TABLES
}

// ---------------- launch: ablation sequence ----------------
extern "C" void kernel_launch(void* const* d_in, const int* in_sizes, int n_in,
                              void* d_out, int out_size, void* d_ws, size_t ws_size,
                              hipStream_t stream) {
    const float* x       = (const float*)d_in[0];
    const float* centers = (const float*)d_in[1];
    const float* widths  = (const float*)d_in[2];
    const float* cons    = (const float*)d_in[3];
    const int*   rules   = (const int*)d_in[4];

    float* out_p     = (float*)d_out;
    float* norm_fs_p = out_p + (size_t)BB * CC;
    float* x_ext_p   = norm_fs_p + (size_t)BB * RR;

    float* wsum4a = (float*)d_ws;
    float* wsum4b = wsum4a + (size_t)RR * 4;
    float* wsum2  = wsum4b + (size_t)RR * 4;
    unsigned int* codes = (unsigned int*)(wsum2 + (size_t)RR * 2);

    prep_kernel<<<(RR * CC + 255) / 256, 256, 0, stream>>>(cons, rules, wsum4a,
                                                           wsum4b, wsum2, codes);

#define LAUNCH_MAIN(VAR) \
    anfis_main<<<BB / TB, 256, 0, stream>>>(x, centers, widths, \
        (const f32x4*)wsum4a, (const f32x4*)wsum4b, (const f32x2*)wsum2, codes, \
        out_p, norm_fs_p, x_ext_p, (VAR))

    // Ablation ladder (timestamp order identifies rows in the counter table):
    LAUNCH_MAIN(V_FULL);               // 1: full
    LAUNCH_MAIN(V_FULL & ~V_STORE);    // 2: no FS/norm_fs stores
    LAUNCH_MAIN(V_FULL & ~V_FMA);      // 3: no wsum loads / acc FMAs
    LAUNCH_MAIN(V_FULL & ~V_GATHER);   // 4: synthetic p (no LDS gathers)
    LAUNCH_MAIN(V_FULL & ~V_TAB);      // 5: no per-rep table rebuild/barriers
    LAUNCH_MAIN(V_FULL);               // 6: full again -> correct final outputs
#undef LAUNCH_MAIN
}

// Round 12
// 96.797 us; speedup vs baseline: 4.8091x; 4.8091x over previous
//
#include <hip/hip_runtime.h>

// Problem constants (match reference)
#define BB 4096
#define DD 16
#define MM 4
#define RR 2048
#define CC 10
#define TB 4
#define RPT (RR / 256)   // rules per thread = 8

typedef __attribute__((ext_vector_type(4))) float f32x4;
typedef __attribute__((ext_vector_type(2))) float f32x2;

// ---------------- prep kernel (unchanged) ----------------
__global__ __launch_bounds__(256) void prep_kernel(
    const float* __restrict__ cons, const int* __restrict__ rules,
    float* __restrict__ wsum4a, float* __restrict__ wsum4b,
    float* __restrict__ wsum2, unsigned int* __restrict__ codes)
{
    int gid = blockIdx.x * 256 + threadIdx.x;
    if (gid < RR * CC) {
        int r = gid / CC, c = gid - r * CC;
        const float* cr = cons + (size_t)r * (DD + 1) * CC + c;
        float s = 0.0f;
#pragma unroll
        for (int j = 0; j < DD + 1; ++j) s += cr[j * CC];
        if (c < 4)      wsum4a[r * 4 + c] = s;
        else if (c < 8) wsum4b[r * 4 + (c - 4)] = s;
        else            wsum2[r * 2 + (c - 8)] = s;
    }
    if (gid < RR) {
        const int* rrp = rules + gid * DD;
        unsigned int code = 0;
#pragma unroll
        for (int g = 0; g < 4; ++g) {
            unsigned int byt = 0;
#pragma unroll
            for (int k = 0; k < 4; ++k)
                byt |= (((unsigned int)rrp[g * 4 + k]) & 3u) << (2 * k);
            code |= byt << (8 * g);
        }
        codes[gid] = code;
    }
}

// Shared table-build fragment (MF -> PAIR4 -> QUAD4), used by both kernels.
#define BUILD_TABLES(QUADP)  do { \
    { int row = tid >> 6, dm = tid & 63, d = dm >> 2, m = dm & 3; \
      float c = centers[d * MM + m]; \
      float w = widths[d * MM + m]; \
      float z = xs[row][d] - c; \
      MF[row][dm] = expf(-(z * z) / (2.0f * w * w)); } \
    __syncthreads(); \
    if (tid < 8 * 16) { \
        int p = tid >> 4, e = tid & 15; \
        int i0 = e & 3, i1 = e >> 2; \
        f32x4 v; \
        _Pragma("unroll") \
        for (int row = 0; row < TB; ++row) \
            v[row] = MF[row][(2 * p) * 4 + i0] * MF[row][(2 * p + 1) * 4 + i1]; \
        PAIR4[p][e] = v; \
    } \
    __syncthreads(); \
    _Pragma("unroll") \
    for (int i = tid; i < 4 * 256; i += 256) { \
        int g = i >> 8, e = i & 255; \
        (QUADP)[g][e] = PAIR4[2 * g][e & 15] * PAIR4[2 * g + 1][e >> 4]; \
    } \
    __syncthreads(); \
} while (0)

// ---------------- kernel A: firing-strength sums + out + x_ext + inv ------
// Single gather pass; acc FMAs are free under the gathers (R11 ablation).
// Writes inv[b] to workspace for kernel B. No norm_fs stores here.
__global__ __launch_bounds__(256, 4) void anfis_sum(
    const float* __restrict__ x, const float* __restrict__ centers,
    const float* __restrict__ widths, const f32x4* __restrict__ wsum4a,
    const f32x4* __restrict__ wsum4b, const f32x2* __restrict__ wsum2,
    const unsigned int* __restrict__ codes,
    float* __restrict__ out, float* __restrict__ x_ext, float* __restrict__ invg)
{
    // QUAD4 (16 KB) aliased with RED (10.9 KB); gathers finish before the
    // phase-3 barriers that precede RED writes.
    __shared__ __align__(16) char pool[4 * 256 * sizeof(f32x4)];
    f32x4 (*QUAD4)[256] = (f32x4 (*)[256])pool;
    float (*RED)[68]    = (float (*)[68])pool;

    __shared__ float MF[TB][64];
    __shared__ f32x4 PAIR4[8][16];
    __shared__ float xs[TB][DD];
    __shared__ float sx[TB];
    __shared__ float wpart[4][TB];
    __shared__ float oscale[TB];
    __shared__ float part2[TB * CC][4];

    const int tid = threadIdx.x;
    const int b0 = blockIdx.x * TB;
    const int lane = tid & 63;
    const int wv = tid >> 6;

    if (tid < TB * (DD + 1)) {
        int row = tid / (DD + 1), col = tid % (DD + 1);
        float v = (col < DD) ? x[(b0 + row) * DD + col] : 1.0f;
        if (col < DD) xs[row][col] = v;
        x_ext[(b0 + row) * (DD + 1) + col] = v;
    }
    __syncthreads();
    if (tid < TB) {
        float s = 1.0f;
#pragma unroll
        for (int d = 0; d < DD; ++d) s += xs[tid][d];
        sx[tid] = s;
    }

    BUILD_TABLES(QUAD4);

    // gather pass: svec + acc
    float acc[TB][CC];
#pragma unroll
    for (int row = 0; row < TB; ++row)
#pragma unroll
        for (int c = 0; c < CC; ++c) acc[row][c] = 0.0f;

    f32x4 svec = {0.0f, 0.0f, 0.0f, 0.0f};

#pragma unroll 1
    for (int j = 0; j < RPT; ++j) {
        int r = tid + 256 * j;
        unsigned int code = codes[r];
        f32x4 q0 = QUAD4[0][code & 255u];
        f32x4 q1 = QUAD4[1][(code >> 8) & 255u];
        f32x4 q2 = QUAD4[2][(code >> 16) & 255u];
        f32x4 q3 = QUAD4[3][code >> 24];
        f32x4 p = (q0 * q1) * (q2 * q3);
        svec += p;

        const f32x4 wa = wsum4a[r];
        const f32x4 wb = wsum4b[r];
        const f32x2 wcp = wsum2[r];
        const float wc[CC] = {wa.x, wa.y, wa.z, wa.w, wb.x,
                              wb.y, wb.z, wb.w, wcp.x, wcp.y};
#pragma unroll
        for (int row = 0; row < TB; ++row)
#pragma unroll
            for (int c = 0; c < CC; ++c)
                acc[row][c] = fmaf(p[row], wc[c], acc[row][c]);
    }

    // block reduce of svec -> inv per row
#pragma unroll
    for (int row = 0; row < TB; ++row) {
        float s = svec[row];
#pragma unroll
        for (int off = 32; off > 0; off >>= 1) s += __shfl_xor(s, off, 64);
        if (lane == 0) wpart[wv][row] = s;
    }
    __syncthreads();
    if (tid < TB) {
        float t = wpart[0][tid] + wpart[1][tid] + wpart[2][tid] + wpart[3][tid];
        float inv = 1.0f / (t + 1e-9f);
        invg[b0 + tid] = inv;
        oscale[tid] = sx[tid] * inv;
    }

    // reduce acc -> out (RED aliases dead QUAD4; barrier first)
    __syncthreads();
#pragma unroll
    for (int row = 0; row < TB; ++row) {
#pragma unroll
        for (int c = 0; c < CC; ++c) {
            float s = acc[row][c];
            s += __shfl_xor(s, 1, 64);
            s += __shfl_xor(s, 2, 64);
            if ((lane & 3) == 0) RED[row * CC + c][wv * 16 + (lane >> 2)] = s;
        }
    }
    __syncthreads();
    if (tid < 160) {
        int v = tid % 40, ch = tid / 40;
        float s = 0.0f;
        int base = ch * 16;
#pragma unroll
        for (int i = 0; i < 16; ++i) s += RED[v][base + i];
        part2[v][ch] = s;
    }
    __syncthreads();
    if (tid < TB * CC) {
        float val = part2[tid][0] + part2[tid][1] + part2[tid][2] + part2[tid][3];
        int row = tid / CC, c = tid % CC;
        out[(b0 + row) * CC + c] = oscale[row] * val;
    }
}

// ---------------- kernel B: normalize + store norm_fs (barrier-free stream) -
// Rebuilds tables, reads inv, then streams gather -> *inv -> coalesced store
// with NO barriers: LDS gathers hide under the mandatory 33 MB HBM write.
__global__ __launch_bounds__(256, 4) void anfis_store(
    const float* __restrict__ x, const float* __restrict__ centers,
    const float* __restrict__ widths, const unsigned int* __restrict__ codes,
    const float* __restrict__ invg, float* __restrict__ norm_fs)
{
    __shared__ __align__(16) f32x4 QUAD4[4][256];
    __shared__ float MF[TB][64];
    __shared__ f32x4 PAIR4[8][16];
    __shared__ float xs[TB][DD];

    const int tid = threadIdx.x;
    const int b0 = blockIdx.x * TB;

    if (tid < TB * DD) {
        int row = tid / DD, d = tid % DD;
        xs[row][d] = x[(b0 + row) * DD + d];
    }
    __syncthreads();

    BUILD_TABLES(QUAD4);

    const float inv0 = invg[b0 + 0];
    const float inv1 = invg[b0 + 1];
    const float inv2 = invg[b0 + 2];
    const float inv3 = invg[b0 + 3];

#pragma unroll 1
    for (int j = 0; j < RPT; ++j) {
        int r = tid + 256 * j;
        unsigned int code = codes[r];
        f32x4 q0 = QUAD4[0][code & 255u];
        f32x4 q1 = QUAD4[1][(code >> 8) & 255u];
        f32x4 q2 = QUAD4[2][(code >> 16) & 255u];
        f32x4 q3 = QUAD4[3][code >> 24];
        f32x4 p = (q0 * q1) * (q2 * q3);
        norm_fs[(size_t)(b0 + 0) * RR + r] = p[0] * inv0;
        norm_fs[(size_t)(b0 + 1) * RR + r] = p[1] * inv1;
        norm_fs[(size_t)(b0 + 2) * RR + r] = p[2] * inv2;
        norm_fs[(size_t)(b0 + 3) * RR + r] = p[3] * inv3;
    }
}

// ---------------- launch ----------------
extern "C" void kernel_launch(void* const* d_in, const int* in_sizes, int n_in,
                              void* d_out, int out_size, void* d_ws, size_t ws_size,
                              hipStream_t stream) {
    const float* x       = (const float*)d_in[0];
    const float* centers = (const float*)d_in[1];
    const float* widths  = (const float*)d_in[2];
    const float* cons    = (const float*)d_in[3];
    const int*   rules   = (const int*)d_in[4];

    float* out_p     = (float*)d_out;                       // (B, C)
    float* norm_fs_p = out_p + (size_t)BB * CC;             // (B, R)
    float* x_ext_p   = norm_fs_p + (size_t)BB * RR;         // (B, D+1)

    // ws: wsum4a 32KB | wsum4b 32KB | wsum2 16KB | codes 8KB | invg 16KB
    float* wsum4a = (float*)d_ws;
    float* wsum4b = wsum4a + (size_t)RR * 4;
    float* wsum2  = wsum4b + (size_t)RR * 4;
    unsigned int* codes = (unsigned int*)(wsum2 + (size_t)RR * 2);
    float* invg   = (float*)(codes + RR);

    prep_kernel<<<(RR * CC + 255) / 256, 256, 0, stream>>>(cons, rules, wsum4a,
                                                           wsum4b, wsum2, codes);
    anfis_sum<<<BB / TB, 256, 0, stream>>>(x, centers, widths,
                                           (const f32x4*)wsum4a,
                                           (const f32x4*)wsum4b,
                                           (const f32x2*)wsum2, codes,
                                           out_p, x_ext_p, invg);
    anfis_store<<<BB / TB, 256, 0, stream>>>(x, centers, widths, codes,
                                             invg, norm_fs_p);
}